// Round 7
// baseline (1265.751 us; speedup 1.0000x reference)
//
#include <hip/hip_runtime.h>
#include <hip/hip_bf16.h>

typedef __hip_bfloat16 bf16;

__device__ __forceinline__ float b2f(bf16 v) { return __bfloat162float(v); }
__device__ __forceinline__ bf16  f2b(float v){ return __float2bfloat16(v); }

// dtype-flexible loads (flags resolved at runtime by sniff_kernel; branches are uniform)
__device__ __forceinline__ float loadF(const void* p, int i, int isf32) {
    return isf32 ? ((const float*)p)[i] : b2f(((const bf16*)p)[i]);
}
__device__ __forceinline__ int loadI(const void* p, long long i, int isi64) {
    return isi64 ? (int)((const long long*)p)[i] : ((const int*)p)[i];
}

// ---------------------------------------------------------------- dtype sniff
__global__ void sniff_kernel(const void* xv, const void* eiv, int* flags) {
    int lane = threadIdx.x;                       // 64 threads
    const bf16* xb = (const bf16*)xv;
    int big = 0;
#pragma unroll
    for (int k = 0; k < 4; k++) {
        float v = fabsf(b2f(xb[lane * 4 + k]));
        if (v > 1e6f) big = 1;
    }
    unsigned long long bigmask = __ballot(big);
    const int* e32 = (const int*)eiv;
    int nz = (lane < 32) ? (e32[2 * lane + 1] != 0) : 0;
    unsigned long long nzmask = __ballot(nz);
    if (lane == 0) {
        flags[0] = (__popcll(bigmask) >= 8) ? 1 : 0;
        flags[1] = (nzmask == 0ULL) ? 1 : 0;
    }
}

// ---------------------------------------------------------------- fills
__global__ void zero_f32(float* __restrict__ p, long long cnt) {
    long long i = (long long)blockIdx.x * blockDim.x + threadIdx.x;
    if (i < cnt) p[i] = 0.f;
}
__global__ void zero_i32(int* __restrict__ p, long long cnt) {
    long long i = (long long)blockIdx.x * blockDim.x + threadIdx.x;
    if (i < cnt) p[i] = 0;
}

// ================================================================ bucket sort (64 nodes / bucket)
__global__ void bucket_count_glob(const void* ei, int* __restrict__ bcnt, int E, int n,
                                  const int* __restrict__ flags) {
    int e = blockIdx.x * blockDim.x + threadIdx.x;
    if (e >= E) return;
    int d = loadI(ei, (long long)E + e, flags[1]);
    if ((unsigned)d < (unsigned)n) atomicAdd(&bcnt[d >> 6], 1);
}

// partial[b] = sum of cnt over chunk b (chunk = 1024)
__global__ void partial_kernel(const int* __restrict__ cnt, int* __restrict__ partial, int n) {
    __shared__ int lds[256];
    int b = blockIdx.x, t = threadIdx.x;
    int base = b * 1024 + t * 4;
    int s = 0;
#pragma unroll
    for (int k = 0; k < 4; k++) { int i = base + k; if (i < n) s += cnt[i]; }
    lds[t] = s; __syncthreads();
    for (int off = 128; off >= 1; off >>= 1) {
        if (t < off) lds[t] += lds[t + off];
        __syncthreads();
    }
    if (t == 0) partial[b] = lds[0];
}

// exclusive scan of partial[] in place (single block); rowptr[n] = total
__global__ void scanpart_kernel(int* __restrict__ partial, int* __restrict__ rowptr,
                                int npart, int n) {
    __shared__ int lds[256];
    int t = threadIdx.x;
    int v = (t < npart) ? partial[t] : 0;
    lds[t] = v; __syncthreads();
    for (int off = 1; off < 256; off <<= 1) {
        int tmp = (t >= off) ? lds[t - off] : 0;
        __syncthreads();
        lds[t] += tmp;
        __syncthreads();
    }
    if (t < npart) partial[t] = lds[t] - v;   // exclusive
    if (t == 0) rowptr[n] = lds[255];         // grand total
}

// rowptr[i] = partial[b] + exclusive-scan within chunk
__global__ void scanblk_kernel(const int* __restrict__ cnt, const int* __restrict__ partial,
                               int* __restrict__ rowptr, int n) {
    __shared__ int lds[256];
    int b = blockIdx.x, t = threadIdx.x;
    int base = b * 1024 + t * 4;
    int v[4]; int ms = 0;
#pragma unroll
    for (int k = 0; k < 4; k++) { int i = base + k; v[k] = (i < n) ? cnt[i] : 0; ms += v[k]; }
    lds[t] = ms; __syncthreads();
    for (int off = 1; off < 256; off <<= 1) {
        int tmp = (t >= off) ? lds[t - off] : 0;
        __syncthreads();
        lds[t] += tmp;
        __syncthreads();
    }
    int p = partial[b] + (lds[t] - ms);
#pragma unroll
    for (int k = 0; k < 4; k++) { int i = base + k; if (i < n) { rowptr[i] = p; p += v[k]; } }
}

// append packed = src | (d&63)<<26 at bucket-sequential position
__global__ void bucket_fill_glob(const void* ei, const int* __restrict__ boff,
                                 int* __restrict__ bcur, unsigned int* __restrict__ packed,
                                 int E, int n, const int* __restrict__ flags) {
    int idf = flags[1];
    int e = blockIdx.x * blockDim.x + threadIdx.x;
    if (e >= E) return;
    int s = loadI(ei, e, idf);
    int d = loadI(ei, (long long)E + e, idf);
    if ((unsigned)s >= (unsigned)n || (unsigned)d >= (unsigned)n) return;
    int b = d >> 6;
    int pos = boff[b] + atomicAdd(&bcur[b], 1);
    packed[pos] = (unsigned)s | ((unsigned)(d & 63) << 26);
}

// per-bucket degree count (from packed list) + dinv + z = [x*dinv(6), dinv, 0]
__global__ void bucket_prep(const unsigned int* __restrict__ packed, const int* __restrict__ boff,
                            const void* xv, float* __restrict__ dinv, float* __restrict__ z,
                            int n, int NB, const int* __restrict__ flags) {
    __shared__ int deg[256];
    int tid = threadIdx.x;
    int w = tid >> 6, lane = tid & 63;    // 4 waves, one bucket each
    int b = blockIdx.x * 4 + w;
    deg[tid] = 0;
    __syncthreads();
    if (b < NB) {
        int beg = boff[b], end = boff[b + 1];
        for (int i = beg + lane; i < end; i += 64)
            atomicAdd(&deg[(w << 6) | (int)(packed[i] >> 26)], 1);
    }
    __syncthreads();
    if (b < NB) {
        int node = (b << 6) + lane;
        if (node < n) {
            int xf = flags[0];
            float dv = rsqrtf((float)deg[tid] + 1.0f);
            dinv[node] = dv;
            float* zr = z + (size_t)node * 8;
#pragma unroll
            for (int k = 0; k < 6; k++) zr[k] = loadF(xv, node * 6 + k, xf) * dv;
            zr[6] = dv; zr[7] = 0.f;
        }
    }
}

// ================================================================ layer 1, bucketed
// S[dl] += z[src] (LDS); finalize: h=relu(dinv*((S+z_self)@W1)+b1); Y2b=bf16((h@W2)*dinv)
__global__ void gcn1_bucket(const unsigned int* __restrict__ packed, const int* __restrict__ boff,
                            const float* __restrict__ z,
                            const void* W1v, const void* b1v, const void* W2v,
                            bf16* __restrict__ Y2b, int n, const int* __restrict__ flags) {
    __shared__ float S[64 * 9];           // 6-dim accum, padded to 9 for banks
    __shared__ float sW1[6 * 32];
    __shared__ float sW2[32 * 32];
    __shared__ float sb1[32];
    int xf = flags[0];
    int tid = threadIdx.x;                // 256
    if (tid < 192) sW1[tid] = loadF(W1v, tid, xf);
    for (int i = tid; i < 1024; i += 256) sW2[i] = loadF(W2v, i, xf);
    if (tid < 32) sb1[tid] = loadF(b1v, tid, xf);
    for (int i = tid; i < 64 * 9; i += 256) S[i] = 0.f;
    __syncthreads();
    int b = blockIdx.x;
    int beg = boff[b], end = boff[b + 1];
    int sub = tid & 7, eg = tid >> 3;     // 32 edge-groups of 8 lanes
    for (int i = beg + eg; i < end; i += 32) {
        unsigned p = packed[i];
        int src = (int)(p & 0x03FFFFFFu);
        int dl  = (int)(p >> 26);
        float v = z[(size_t)src * 8 + sub];   // 32B coalesced per group
        if (sub < 6) atomicAdd(&S[dl * 9 + sub], v);
    }
    __syncthreads();
    int j = tid & 31;
    for (int ib = 0; ib < 8; ib++) {
        int il = ib * 8 + (tid >> 5);
        int node = (b << 6) + il;
        if (node < n) {                   // uniform per 32-lane group
            const float* zs = z + (size_t)node * 8;
            float dv = zs[6];
            float v = (S[il * 9 + 0] + zs[0]) * sW1[j];
            v = fmaf(S[il * 9 + 1] + zs[1], sW1[32 + j], v);
            v = fmaf(S[il * 9 + 2] + zs[2], sW1[64 + j], v);
            v = fmaf(S[il * 9 + 3] + zs[3], sW1[96 + j], v);
            v = fmaf(S[il * 9 + 4] + zs[4], sW1[128 + j], v);
            v = fmaf(S[il * 9 + 5] + zs[5], sW1[160 + j], v);
            float h = fmaxf(fmaf(dv, v, sb1[j]), 0.f);
            float y2 = 0.f;
#pragma unroll
            for (int kk = 0; kk < 32; kk++) y2 = fmaf(__shfl(h, kk, 32), sW2[kk * 32 + j], y2);
            Y2b[(size_t)node * 32 + j] = f2b(y2 * dv);
        }
    }
}

// ================================================================ layer 2, bucketed + heads
// out layout (f32): [logits n][normals 3n][uvs 3n][features 32n]
__global__ void gcn2_bucket(const unsigned int* __restrict__ packed, const int* __restrict__ boff,
                            const bf16* __restrict__ Y2b, const float* __restrict__ dinv,
                            const void* b2v,
                            const void* Wt1v, const void* bt1v, const void* Wt2v, const void* bt2v,
                            const void* Wa1v, const void* ba1v, const void* Wa2v, const void* ba2v,
                            float* __restrict__ out, int n, const int* __restrict__ flags) {
    __shared__ float F[64 * 32];          // 8 KB accum
    __shared__ float sWt1[512], sWa1[512], sWt2[16], sWa2[96];
    __shared__ float sbt1[16], sba1[16], sba2[6], sb2[32];
    __shared__ float sbt2;
    int xf = flags[0];
    int tid = threadIdx.x;                // 256
    for (int i = tid; i < 512; i += 256) { sWt1[i] = loadF(Wt1v, i, xf); sWa1[i] = loadF(Wa1v, i, xf); }
    if (tid < 96) sWa2[tid] = loadF(Wa2v, tid, xf);
    if (tid < 16) { sWt2[tid] = loadF(Wt2v, tid, xf); sbt1[tid] = loadF(bt1v, tid, xf); sba1[tid] = loadF(ba1v, tid, xf); }
    if (tid < 32) sb2[tid] = loadF(b2v, tid, xf);
    if (tid < 6) sba2[tid] = loadF(ba2v, tid, xf);
    if (tid == 0) sbt2 = loadF(bt2v, 0, xf);
    for (int i = tid; i < 2048; i += 256) F[i] = 0.f;
    __syncthreads();
    int b = blockIdx.x;
    int beg = boff[b], end = boff[b + 1];
    int j = tid & 31, eg = tid >> 5;      // 8 edge-groups of 32 lanes
    for (int i = beg + eg; i < end; i += 8) {
        unsigned p = packed[i];
        int src = (int)(p & 0x03FFFFFFu);
        int dl  = (int)(p >> 26);
        atomicAdd(&F[dl * 32 + j], b2f(Y2b[(size_t)src * 32 + j]));  // 64B coalesced gather
    }
    __syncthreads();
    for (int ib = 0; ib < 8; ib++) {
        int il = ib * 8 + (tid >> 5);
        int node = (b << 6) + il;
        if (node >= n) continue;          // uniform per group
        float dv = dinv[node];
        float f = fmaf(dv, F[il * 32 + j] + b2f(Y2b[(size_t)node * 32 + j]), sb2[j]);
        out[(size_t)n * 7 + (size_t)node * 32 + j] = f;   // features
        float acc = 0.f;
#pragma unroll
        for (int k = 0; k < 32; k++) {
            float fk = __shfl(f, k, 32);
            float w = (j < 16) ? sWt1[k * 16 + j] : sWa1[k * 16 + (j - 16)];
            acc = fmaf(fk, w, acc);
        }
        float u = fmaxf(acc + ((j < 16) ? sbt1[j] : sba1[j - 16]), 0.f);
        float o = 0.f;
#pragma unroll
        for (int k = 0; k < 16; k++) {
            float ut = __shfl(u, k, 32);
            float ua = __shfl(u, 16 + k, 32);
            float w = (j == 0) ? sWt2[k] : ((j < 7) ? sWa2[k * 6 + (j - 1)] : 0.f);
            o = fmaf((j == 0) ? ut : ua, w, o);
        }
        if (j == 0)      out[node] = o + sbt2;
        else if (j < 4)  out[(size_t)n     + (size_t)node * 3 + (j - 1)] = o + sba2[j - 1];
        else if (j < 7)  out[(size_t)n * 4 + (size_t)node * 3 + (j - 4)] = o + sba2[j - 1];
    }
}

// ================================================================ fallback (round-4 scatter path)
__global__ void count_kernel(const void* ei, float* __restrict__ deg, int E, int n,
                             const int* __restrict__ flags) {
    int e = blockIdx.x * blockDim.x + threadIdx.x;
    if (e >= E) return;
    int d = loadI(ei, (long long)E + e, flags[1]);
    if ((unsigned)d < (unsigned)n) atomicAdd(&deg[d], 1.0f);
}
__global__ void dinv_kernel(float* __restrict__ dinv, int n) {
    int i = blockIdx.x * blockDim.x + threadIdx.x;
    if (i < n) dinv[i] = rsqrtf(dinv[i] + 1.0f);
}
__global__ void scatter1_kernel(const void* ei, const void* xv, const void* W1v,
                                const float* __restrict__ dinv, float* __restrict__ A,
                                int E, int n, const int* __restrict__ flags) {
    __shared__ float sW1[6 * 32];
    int xf = flags[0], idf = flags[1];
    int tid = threadIdx.x;
    if (tid < 192) sW1[tid] = loadF(W1v, tid, xf);
    __syncthreads();
    long long t = (long long)blockIdx.x * blockDim.x + tid;
    int e = (int)(t >> 5), j = (int)(t & 31);
    if (e >= E) return;
    int s = loadI(ei, e, idf);
    int d = loadI(ei, (long long)E + e, idf);
    if ((unsigned)s >= (unsigned)n || (unsigned)d >= (unsigned)n) return;
    float dv = dinv[s];
    float y = 0.f;
#pragma unroll
    for (int k = 0; k < 6; k++) y = fmaf(loadF(xv, s * 6 + k, xf), sW1[k * 32 + j], y);
    atomicAdd(&A[(size_t)d * 32 + j], y * dv);
}
__global__ void fused_mid_kernel(const float* __restrict__ A, const void* xv,
                                 const float* __restrict__ dinv,
                                 const void* W1v, const void* b1v, const void* W2v,
                                 float* __restrict__ Yf, int n, const int* __restrict__ flags) {
    __shared__ float sW1[6 * 32];
    __shared__ float sW2[32 * 32];
    __shared__ float sb1[32];
    int xf = flags[0];
    int tid = threadIdx.x;
    if (tid < 192) sW1[tid] = loadF(W1v, tid, xf);
    for (int i = tid; i < 32 * 32; i += blockDim.x) sW2[i] = loadF(W2v, i, xf);
    if (tid < 32) sb1[tid] = loadF(b1v, tid, xf);
    __syncthreads();
    long long t = (long long)blockIdx.x * blockDim.x + tid;
    int node = (int)(t >> 5), j = (int)(t & 31);
    if (node >= n) return;
    float dv = dinv[node];
    float xw = 0.f;
#pragma unroll
    for (int k = 0; k < 6; k++) xw = fmaf(loadF(xv, node * 6 + k, xf), sW1[k * 32 + j], xw);
    float h = fmaxf(dv * A[t] + dv * dv * xw + sb1[j], 0.f);
    float y2 = 0.f;
#pragma unroll
    for (int k = 0; k < 32; k++) y2 = fmaf(__shfl(h, k, 32), sW2[k * 32 + j], y2);
    Yf[t] = y2 * dv;
}
__global__ void scatter2_kernel(const void* ei, const float* __restrict__ Yf,
                                float* __restrict__ A, int E, int n,
                                const int* __restrict__ flags) {
    int idf = flags[1];
    long long t = (long long)blockIdx.x * blockDim.x + threadIdx.x;
    int e = (int)(t >> 5), j = (int)(t & 31);
    if (e >= E) return;
    int s = loadI(ei, e, idf);
    int d = loadI(ei, (long long)E + e, idf);
    if ((unsigned)s >= (unsigned)n || (unsigned)d >= (unsigned)n) return;
    atomicAdd(&A[(size_t)d * 32 + j], Yf[(size_t)s * 32 + j]);
}
__global__ void out_kernel(const float* __restrict__ A, const float* __restrict__ dinv,
                           const void* b2v,
                           const void* Wt1v, const void* bt1v, const void* Wt2v, const void* bt2v,
                           const void* Wa1v, const void* ba1v, const void* Wa2v, const void* ba2v,
                           float* __restrict__ out, int n, const int* __restrict__ flags) {
    __shared__ float sWt1[32 * 16], sWa1[32 * 16], sWt2[16], sWa2[16 * 6];
    __shared__ float sbt1[16], sba1[16], sba2[6], sb2[32];
    __shared__ float sbt2;
    int xf = flags[0];
    int tid = threadIdx.x;
    for (int i = tid; i < 32 * 16; i += blockDim.x) { sWt1[i] = loadF(Wt1v, i, xf); sWa1[i] = loadF(Wa1v, i, xf); }
    for (int i = tid; i < 16 * 6; i += blockDim.x) sWa2[i] = loadF(Wa2v, i, xf);
    if (tid < 16) { sWt2[tid] = loadF(Wt2v, tid, xf); sbt1[tid] = loadF(bt1v, tid, xf); sba1[tid] = loadF(ba1v, tid, xf); }
    if (tid < 32) sb2[tid] = loadF(b2v, tid, xf);
    if (tid < 6) sba2[tid] = loadF(ba2v, tid, xf);
    if (tid == 0) sbt2 = loadF(bt2v, 0, xf);
    __syncthreads();
    long long t = (long long)blockIdx.x * blockDim.x + tid;
    int node = (int)(t >> 5), j = (int)(t & 31);
    if (node >= n) return;
    float* Yf = out + (size_t)n * 7;
    float dv = dinv[node];
    float f = dv * (A[t] + Yf[t]) + sb2[j];
    Yf[t] = f;
    float acc = 0.f;
#pragma unroll
    for (int k = 0; k < 32; k++) {
        float fk = __shfl(f, k, 32);
        float w = (j < 16) ? sWt1[k * 16 + j] : sWa1[k * 16 + (j - 16)];
        acc = fmaf(fk, w, acc);
    }
    float u = fmaxf(acc + ((j < 16) ? sbt1[j] : sba1[j - 16]), 0.f);
    float o = 0.f;
#pragma unroll
    for (int k = 0; k < 16; k++) {
        float ut = __shfl(u, k, 32);
        float ua = __shfl(u, 16 + k, 32);
        float w = (j == 0) ? sWt2[k] : ((j < 7) ? sWa2[k * 6 + (j - 1)] : 0.f);
        o = fmaf((j == 0) ? ut : ua, w, o);
    }
    if (j == 0)      out[node] = o + sbt2;
    else if (j < 4)  out[(size_t)n     + (size_t)node * 3 + (j - 1)] = o + sba2[j - 1];
    else if (j < 7)  out[(size_t)n * 4 + (size_t)node * 3 + (j - 4)] = o + sba2[j - 1];
}

extern "C" void kernel_launch(void* const* d_in, const int* in_sizes, int n_in,
                              void* d_out, int out_size, void* d_ws, size_t ws_size,
                              hipStream_t stream) {
    const void* x   = d_in[0];
    const void* ei  = d_in[1];
    const void* W1  = d_in[2];
    const void* b1  = d_in[3];
    const void* W2  = d_in[4];
    const void* b2  = d_in[5];
    const void* Wt1 = d_in[6];
    const void* bt1 = d_in[7];
    const void* Wt2 = d_in[8];
    const void* bt2 = d_in[9];
    const void* Wa1 = d_in[10];
    const void* ba1 = d_in[11];
    const void* Wa2 = d_in[12];
    const void* ba2 = d_in[13];

    int n = in_sizes[0] / 6;          // 150000
    int E = in_sizes[1] / 2;          // 2400000

    const int B = 256;
    float* out = (float*)d_out;
    char* ws = (char*)d_ws;

    // ---------------- bucketed-path workspace layout (4B words; 64w-aligned regions) ----
    int NB = (n + 63) >> 6;
    size_t NBw = (size_t)((NB + 63) & ~63);
    size_t nw  = (size_t)((n + 63) & ~63);
    size_t Ew  = (size_t)((E + 63) & ~63);
    size_t w_bcnt = 0;
    size_t w_bcur = NBw;
    size_t w_boff = 2 * NBw;               // NB+1 entries
    size_t w_par  = w_boff + NBw + 64;
    size_t w_flg  = w_par + 256;
    size_t w_div  = w_flg + 64;
    size_t w_z    = w_div + nw;            // n x 8 f32 (32B rows)
    size_t w_pack = w_z + 8 * nw;
    size_t w_y2b  = w_pack + Ew;           // n x 32 bf16 (64B rows)
    size_t need   = (w_y2b + 16 * nw) * 4;

    if (ws_size >= need && n < (1 << 26)) {
        int*      bcnt    = (int*)(ws + w_bcnt * 4);
        int*      bcur    = (int*)(ws + w_bcur * 4);
        int*      boff    = (int*)(ws + w_boff * 4);
        int*      partial = (int*)(ws + w_par * 4);
        int*      flags   = (int*)(ws + w_flg * 4);
        float*    dinv    = (float*)(ws + w_div * 4);
        float*    z       = (float*)(ws + w_z * 4);
        unsigned* packed  = (unsigned*)(ws + w_pack * 4);
        bf16*     Y2b     = (bf16*)(ws + w_y2b * 4);

        int npart = (NB + 1023) / 1024;
        int grid_e = (E + B - 1) / B;

        sniff_kernel<<<1, 64, 0, stream>>>(x, ei, flags);
        zero_i32<<<(int)((2 * NBw + B - 1) / B), B, 0, stream>>>(bcnt, (long long)(2 * NBw)); // bcnt+bcur
        bucket_count_glob<<<grid_e, B, 0, stream>>>(ei, bcnt, E, n, flags);
        partial_kernel<<<npart, B, 0, stream>>>(bcnt, partial, NB);
        scanpart_kernel<<<1, B, 0, stream>>>(partial, boff, npart, NB);
        scanblk_kernel<<<npart, B, 0, stream>>>(bcnt, partial, boff, NB);
        bucket_fill_glob<<<grid_e, B, 0, stream>>>(ei, boff, bcur, packed, E, n, flags);
        bucket_prep<<<(NB + 3) / 4, B, 0, stream>>>(packed, boff, x, dinv, z, n, NB, flags);
        gcn1_bucket<<<NB, B, 0, stream>>>(packed, boff, z, W1, b1, W2, Y2b, n, flags);
        gcn2_bucket<<<NB, B, 0, stream>>>(packed, boff, Y2b, dinv, b2,
                                          Wt1, bt1, Wt2, bt2, Wa1, ba1, Wa2, ba2,
                                          out, n, flags);
        return;
    }

    // ---------------- fallback: round-4 scatter path ----------------
    size_t n_pad = (size_t)((n + 63) & ~63);
    float* A     = (float*)ws;
    float* dinvF = (float*)(ws + (size_t)32 * n * 4);
    int* flagsF  = (int*)(ws + ((size_t)32 * n + n_pad) * 4);
    float* Yf    = out + (size_t)n * 7;

    long long zcnt = (long long)32 * n + (long long)n_pad;
    int grid_zero  = (int)((zcnt + B - 1) / B);
    int grid_zeroA = (int)(((long long)32 * n + B - 1) / B);
    int grid_nodes = (int)(((long long)n * 32 + B - 1) / B);
    int grid_edges = (int)(((long long)E * 32 + B - 1) / B);

    sniff_kernel<<<1, 64, 0, stream>>>(x, ei, flagsF);
    zero_f32<<<grid_zero, B, 0, stream>>>(A, zcnt);
    count_kernel<<<(E + B - 1) / B, B, 0, stream>>>(ei, dinvF, E, n, flagsF);
    dinv_kernel<<<(n + B - 1) / B, B, 0, stream>>>(dinvF, n);
    scatter1_kernel<<<grid_edges, B, 0, stream>>>(ei, x, W1, dinvF, A, E, n, flagsF);
    fused_mid_kernel<<<grid_nodes, B, 0, stream>>>(A, x, dinvF, W1, b1, W2, Yf, n, flagsF);
    zero_f32<<<grid_zeroA, B, 0, stream>>>(A, (long long)32 * n);
    scatter2_kernel<<<grid_edges, B, 0, stream>>>(ei, Yf, A, E, n, flagsF);
    out_kernel<<<grid_nodes, B, 0, stream>>>(A, dinvF, b2, Wt1, bt1, Wt2, bt2,
                                             Wa1, ba1, Wa2, ba2, out, n, flagsF);
}

// Round 8
// 816.902 us; speedup vs baseline: 1.5495x; 1.5495x over previous
//
#include <hip/hip_runtime.h>
#include <hip/hip_bf16.h>

typedef __hip_bfloat16 bf16;

__device__ __forceinline__ float b2f(bf16 v) { return __bfloat162float(v); }
__device__ __forceinline__ bf16  f2b(float v){ return __float2bfloat16(v); }

// dtype-flexible loads (flags resolved at runtime by sniff_kernel; branches are uniform)
__device__ __forceinline__ float loadF(const void* p, int i, int isf32) {
    return isf32 ? ((const float*)p)[i] : b2f(((const bf16*)p)[i]);
}
__device__ __forceinline__ int loadI(const void* p, long long i, int isi64) {
    return isi64 ? (int)((const long long*)p)[i] : ((const int*)p)[i];
}

// ---------------------------------------------------------------- dtype sniff
__global__ void sniff_kernel(const void* xv, const void* eiv, int* flags) {
    int lane = threadIdx.x;                       // 64 threads
    const bf16* xb = (const bf16*)xv;
    int big = 0;
#pragma unroll
    for (int k = 0; k < 4; k++) {
        float v = fabsf(b2f(xb[lane * 4 + k]));
        if (v > 1e6f) big = 1;
    }
    unsigned long long bigmask = __ballot(big);
    const int* e32 = (const int*)eiv;
    int nz = (lane < 32) ? (e32[2 * lane + 1] != 0) : 0;
    unsigned long long nzmask = __ballot(nz);
    if (lane == 0) {
        flags[0] = (__popcll(bigmask) >= 8) ? 1 : 0;
        flags[1] = (nzmask == 0ULL) ? 1 : 0;
    }
}

// ---------------------------------------------------------------- fills
__global__ void zero_f32(float* __restrict__ p, long long cnt) {
    long long i = (long long)blockIdx.x * blockDim.x + threadIdx.x;
    if (i < cnt) p[i] = 0.f;
}
__global__ void zero_i32(int* __restrict__ p, long long cnt) {
    long long i = (long long)blockIdx.x * blockDim.x + threadIdx.x;
    if (i < cnt) p[i] = 0;
}

// ================================================================ bucket build (64 nodes / bucket)
__global__ void bucket_count_glob(const void* ei, int* __restrict__ bcnt, int E, int n,
                                  const int* __restrict__ flags) {
    int e = blockIdx.x * blockDim.x + threadIdx.x;
    if (e >= E) return;
    int d = loadI(ei, (long long)E + e, flags[1]);
    if ((unsigned)d < (unsigned)n) atomicAdd(&bcnt[d >> 6], 1);
}

// partial[b] = sum of cnt over chunk b (chunk = 1024)
__global__ void partial_kernel(const int* __restrict__ cnt, int* __restrict__ partial, int n) {
    __shared__ int lds[256];
    int b = blockIdx.x, t = threadIdx.x;
    int base = b * 1024 + t * 4;
    int s = 0;
#pragma unroll
    for (int k = 0; k < 4; k++) { int i = base + k; if (i < n) s += cnt[i]; }
    lds[t] = s; __syncthreads();
    for (int off = 128; off >= 1; off >>= 1) {
        if (t < off) lds[t] += lds[t + off];
        __syncthreads();
    }
    if (t == 0) partial[b] = lds[0];
}

// exclusive scan of partial[] in place (single block); rowptr[n] = total
__global__ void scanpart_kernel(int* __restrict__ partial, int* __restrict__ rowptr,
                                int npart, int n) {
    __shared__ int lds[256];
    int t = threadIdx.x;
    int v = (t < npart) ? partial[t] : 0;
    lds[t] = v; __syncthreads();
    for (int off = 1; off < 256; off <<= 1) {
        int tmp = (t >= off) ? lds[t - off] : 0;
        __syncthreads();
        lds[t] += tmp;
        __syncthreads();
    }
    if (t < npart) partial[t] = lds[t] - v;   // exclusive
    if (t == 0) rowptr[n] = lds[255];         // grand total
}

// rowptr[i] = partial[b] + exclusive-scan within chunk
__global__ void scanblk_kernel(const int* __restrict__ cnt, const int* __restrict__ partial,
                               int* __restrict__ rowptr, int n) {
    __shared__ int lds[256];
    int b = blockIdx.x, t = threadIdx.x;
    int base = b * 1024 + t * 4;
    int v[4]; int ms = 0;
#pragma unroll
    for (int k = 0; k < 4; k++) { int i = base + k; v[k] = (i < n) ? cnt[i] : 0; ms += v[k]; }
    lds[t] = ms; __syncthreads();
    for (int off = 1; off < 256; off <<= 1) {
        int tmp = (t >= off) ? lds[t - off] : 0;
        __syncthreads();
        lds[t] += tmp;
        __syncthreads();
    }
    int p = partial[b] + (lds[t] - ms);
#pragma unroll
    for (int k = 0; k < 4; k++) { int i = base + k; if (i < n) { rowptr[i] = p; p += v[k]; } }
}

// append packed = src | (d&63)<<26 at bucket-sequential position
__global__ void bucket_fill_glob(const void* ei, const int* __restrict__ boff,
                                 int* __restrict__ bcur, unsigned int* __restrict__ packed,
                                 int E, int n, const int* __restrict__ flags) {
    int idf = flags[1];
    int e = blockIdx.x * blockDim.x + threadIdx.x;
    if (e >= E) return;
    int s = loadI(ei, e, idf);
    int d = loadI(ei, (long long)E + e, idf);
    if ((unsigned)s >= (unsigned)n || (unsigned)d >= (unsigned)n) return;
    int b = d >> 6;
    int pos = boff[b] + atomicAdd(&bcur[b], 1);
    packed[pos] = (unsigned)s | ((unsigned)(d & 63) << 26);
}

// per-bucket LDS counting sort: packed (bucket-grouped) -> adj (node-grouped) + rowptr
#define BSCAP 8192
__global__ void bucket_sort(const unsigned int* __restrict__ packed, const int* __restrict__ boff,
                            int* __restrict__ rowptr, int* __restrict__ adj, int n, int NB) {
    __shared__ int deg[64], cum[64], cur[64];
    __shared__ unsigned int buf[BSCAP];       // 32 KB stage
    int b = blockIdx.x, tid = threadIdx.x;    // 256 threads
    int beg = boff[b], end = boff[b + 1], len = end - beg;
    if (tid < 64) { deg[tid] = 0; cur[tid] = 0; }
    __syncthreads();
    bool fits = (len <= BSCAP);
    for (int i = tid; i < len; i += 256) {
        unsigned p = packed[beg + i];
        if (fits) buf[i] = p;
        atomicAdd(&deg[p >> 26], 1);
    }
    __syncthreads();
    if (tid < 64) {                           // wave-0 exclusive scan over 64 counters
        int v = deg[tid];
        int inc = v;
#pragma unroll
        for (int off = 1; off < 64; off <<= 1) {
            int t2 = __shfl_up(inc, off, 64);
            if (tid >= off) inc += t2;
        }
        cum[tid] = inc - v;
        int node = (b << 6) + tid;
        if (node <= n) rowptr[node] = beg + (inc - v);
    }
    if (b == 0 && tid == 0) rowptr[n] = boff[NB];
    __syncthreads();
    for (int i = tid; i < len; i += 256) {
        unsigned p = fits ? buf[i] : packed[beg + i];
        int dl = (int)(p >> 26);
        int pos = beg + cum[dl] + atomicAdd(&cur[dl], 1);
        adj[pos] = (int)(p & 0x03FFFFFFu);    // 4KB bucket window: cache-friendly
    }
}

// dinv + z = [x*dinv(6), dinv, 0] from rowptr degree
__global__ void prep2_kernel(const int* __restrict__ rowptr, const void* xv,
                             float* __restrict__ dinv, float* __restrict__ z,
                             int n, const int* __restrict__ flags) {
    int i = blockIdx.x * blockDim.x + threadIdx.x;
    if (i >= n) return;
    int xf = flags[0];
    int deg = rowptr[i + 1] - rowptr[i];
    float dv = rsqrtf((float)deg + 1.0f);
    dinv[i] = dv;
    float* zr = z + (size_t)i * 8;
#pragma unroll
    for (int k = 0; k < 6; k++) zr[k] = loadF(xv, i * 6 + k, xf) * dv;
    zr[6] = dv; zr[7] = 0.f;
}

// ================================================================ layer 1: per-node gather (proven round-6 code)
__global__ void gcn1_kernel(const int* __restrict__ rowptr, const int* __restrict__ adj,
                            const float* __restrict__ z,
                            const void* W1v, const void* b1v, const void* W2v,
                            bf16* __restrict__ Y2b, int n, const int* __restrict__ flags) {
    __shared__ float sW1[6 * 32];
    __shared__ float sW2[32 * 32];
    __shared__ float sb1[32];
    int xf = flags[0];
    int tid = threadIdx.x;
    if (tid < 192) sW1[tid] = loadF(W1v, tid, xf);
    for (int i = tid; i < 1024; i += blockDim.x) sW2[i] = loadF(W2v, i, xf);
    if (tid < 32) sb1[tid] = loadF(b1v, tid, xf);
    __syncthreads();
    long long t = (long long)blockIdx.x * blockDim.x + tid;
    int node = (int)(t >> 5), j = (int)(t & 31);
    if (node >= n) return;
    int base = rowptr[node], end = rowptr[node + 1];
    // 16 edges per iteration: lane pair (j>>1) owns one edge, (j&1) picks float4 half of 32B z row
    float a0 = 0.f, a1 = 0.f, a2 = 0.f, a3 = 0.f;
    int half4 = (j & 1) * 4;
    for (int i0 = base; i0 < end; i0 += 16) {
        int eidx = i0 + (j >> 1);
        if (eidx < end) {
            int s = adj[eidx];
            const float4 v = *(const float4*)(z + (size_t)s * 8 + half4);
            a0 += v.x; a1 += v.y; a2 += v.z; a3 += v.w;
        }
    }
#pragma unroll
    for (int off = 2; off <= 16; off <<= 1) {
        a0 += __shfl_xor(a0, off, 32); a1 += __shfl_xor(a1, off, 32);
        a2 += __shfl_xor(a2, off, 32); a3 += __shfl_xor(a3, off, 32);
    }
    float S0 = __shfl(a0, 0, 32), S1 = __shfl(a1, 0, 32), S2 = __shfl(a2, 0, 32);
    float S3 = __shfl(a3, 0, 32), S4 = __shfl(a0, 1, 32), S5 = __shfl(a1, 1, 32);
    const float* zs = z + (size_t)node * 8;   // uniform within group (broadcast)
    float dv = zs[6];
    S0 += zs[0]; S1 += zs[1]; S2 += zs[2]; S3 += zs[3]; S4 += zs[4]; S5 += zs[5];
    float v = S0 * sW1[j];
    v = fmaf(S1, sW1[32 + j], v);
    v = fmaf(S2, sW1[64 + j], v);
    v = fmaf(S3, sW1[96 + j], v);
    v = fmaf(S4, sW1[128 + j], v);
    v = fmaf(S5, sW1[160 + j], v);
    float h = fmaxf(fmaf(dv, v, sb1[j]), 0.f);
    float y2 = 0.f;
#pragma unroll
    for (int kk = 0; kk < 32; kk++) y2 = fmaf(__shfl(h, kk, 32), sW2[kk * 32 + j], y2);
    Y2b[(size_t)node * 32 + j] = f2b(y2 * dv);
}

// ================================================================ layer 2: per-node bf16 gather + heads (proven round-6 code)
// out layout (f32): [logits n][normals 3n][uvs 3n][features 32n]
__global__ void gcn2_kernel(const int* __restrict__ rowptr, const int* __restrict__ adj,
                            const bf16* __restrict__ Y2b, const float* __restrict__ dinv,
                            const void* b2v,
                            const void* Wt1v, const void* bt1v, const void* Wt2v, const void* bt2v,
                            const void* Wa1v, const void* ba1v, const void* Wa2v, const void* ba2v,
                            float* __restrict__ out, int n, const int* __restrict__ flags) {
    __shared__ float sWt1[32 * 16], sWa1[32 * 16], sWt2[16], sWa2[16 * 6];
    __shared__ float sbt1[16], sba1[16], sba2[6], sb2[32];
    __shared__ float sbt2;
    int xf = flags[0];
    int tid = threadIdx.x;
    for (int i = tid; i < 32 * 16; i += blockDim.x) {
        sWt1[i] = loadF(Wt1v, i, xf);
        sWa1[i] = loadF(Wa1v, i, xf);
    }
    for (int i = tid; i < 16 * 6; i += blockDim.x) sWa2[i] = loadF(Wa2v, i, xf);
    if (tid < 16) { sWt2[tid] = loadF(Wt2v, tid, xf); sbt1[tid] = loadF(bt1v, tid, xf); sba1[tid] = loadF(ba1v, tid, xf); }
    if (tid < 32) sb2[tid] = loadF(b2v, tid, xf);
    if (tid < 6) sba2[tid] = loadF(ba2v, tid, xf);
    if (tid == 0) sbt2 = loadF(bt2v, 0, xf);
    __syncthreads();
    long long t = (long long)blockIdx.x * blockDim.x + tid;
    int node = (int)(t >> 5), j = (int)(t & 31);
    if (node >= n) return;
    int base = rowptr[node], end = rowptr[node + 1];
    float agg = 0.f;
    for (int i0 = base; i0 < end; i0 += 32) {
        int rem = end - i0;
        int sv = (j < rem) ? adj[i0 + j] : 0;
        int mm = (rem < 32) ? rem : 32;
        int kk = 0;
        for (; kk + 4 <= mm; kk += 4) {
            int s0 = __shfl(sv, kk, 32), s1 = __shfl(sv, kk + 1, 32);
            int s2 = __shfl(sv, kk + 2, 32), s3 = __shfl(sv, kk + 3, 32);
            float q0 = b2f(Y2b[(size_t)s0 * 32 + j]);
            float q1 = b2f(Y2b[(size_t)s1 * 32 + j]);
            float q2 = b2f(Y2b[(size_t)s2 * 32 + j]);
            float q3 = b2f(Y2b[(size_t)s3 * 32 + j]);
            agg += (q0 + q1) + (q2 + q3);
        }
        for (; kk < mm; kk++) {
            int s0 = __shfl(sv, kk, 32);
            agg += b2f(Y2b[(size_t)s0 * 32 + j]);
        }
    }
    float dv = dinv[node];
    float f = fmaf(dv, agg + b2f(Y2b[(size_t)node * 32 + j]), sb2[j]);
    __builtin_nontemporal_store(f, &out[(size_t)n * 7 + (size_t)node * 32 + j]);  // features
    float acc = 0.f;
#pragma unroll
    for (int k = 0; k < 32; k++) {
        float fk = __shfl(f, k, 32);
        float w = (j < 16) ? sWt1[k * 16 + j] : sWa1[k * 16 + (j - 16)];
        acc = fmaf(fk, w, acc);
    }
    float u = fmaxf(acc + ((j < 16) ? sbt1[j] : sba1[j - 16]), 0.f);
    float o = 0.f;
#pragma unroll
    for (int k = 0; k < 16; k++) {
        float ut = __shfl(u, k, 32);
        float ua = __shfl(u, 16 + k, 32);
        float w = (j == 0) ? sWt2[k] : ((j < 7) ? sWa2[k * 6 + (j - 1)] : 0.f);
        o = fmaf((j == 0) ? ut : ua, w, o);
    }
    if (j == 0)      out[node] = o + sbt2;
    else if (j < 4)  out[(size_t)n     + (size_t)node * 3 + (j - 1)] = o + sba2[j - 1];
    else if (j < 7)  out[(size_t)n * 4 + (size_t)node * 3 + (j - 4)] = o + sba2[j - 1];
}

// ================================================================ fallback (round-4 scatter path)
__global__ void count_kernel(const void* ei, float* __restrict__ deg, int E, int n,
                             const int* __restrict__ flags) {
    int e = blockIdx.x * blockDim.x + threadIdx.x;
    if (e >= E) return;
    int d = loadI(ei, (long long)E + e, flags[1]);
    if ((unsigned)d < (unsigned)n) atomicAdd(&deg[d], 1.0f);
}
__global__ void dinv_kernel(float* __restrict__ dinv, int n) {
    int i = blockIdx.x * blockDim.x + threadIdx.x;
    if (i < n) dinv[i] = rsqrtf(dinv[i] + 1.0f);
}
__global__ void scatter1_kernel(const void* ei, const void* xv, const void* W1v,
                                const float* __restrict__ dinv, float* __restrict__ A,
                                int E, int n, const int* __restrict__ flags) {
    __shared__ float sW1[6 * 32];
    int xf = flags[0], idf = flags[1];
    int tid = threadIdx.x;
    if (tid < 192) sW1[tid] = loadF(W1v, tid, xf);
    __syncthreads();
    long long t = (long long)blockIdx.x * blockDim.x + tid;
    int e = (int)(t >> 5), j = (int)(t & 31);
    if (e >= E) return;
    int s = loadI(ei, e, idf);
    int d = loadI(ei, (long long)E + e, idf);
    if ((unsigned)s >= (unsigned)n || (unsigned)d >= (unsigned)n) return;
    float dv = dinv[s];
    float y = 0.f;
#pragma unroll
    for (int k = 0; k < 6; k++) y = fmaf(loadF(xv, s * 6 + k, xf), sW1[k * 32 + j], y);
    atomicAdd(&A[(size_t)d * 32 + j], y * dv);
}
__global__ void fused_mid_kernel(const float* __restrict__ A, const void* xv,
                                 const float* __restrict__ dinv,
                                 const void* W1v, const void* b1v, const void* W2v,
                                 float* __restrict__ Yf, int n, const int* __restrict__ flags) {
    __shared__ float sW1[6 * 32];
    __shared__ float sW2[32 * 32];
    __shared__ float sb1[32];
    int xf = flags[0];
    int tid = threadIdx.x;
    if (tid < 192) sW1[tid] = loadF(W1v, tid, xf);
    for (int i = tid; i < 32 * 32; i += blockDim.x) sW2[i] = loadF(W2v, i, xf);
    if (tid < 32) sb1[tid] = loadF(b1v, tid, xf);
    __syncthreads();
    long long t = (long long)blockIdx.x * blockDim.x + tid;
    int node = (int)(t >> 5), j = (int)(t & 31);
    if (node >= n) return;
    float dv = dinv[node];
    float xw = 0.f;
#pragma unroll
    for (int k = 0; k < 6; k++) xw = fmaf(loadF(xv, node * 6 + k, xf), sW1[k * 32 + j], xw);
    float h = fmaxf(dv * A[t] + dv * dv * xw + sb1[j], 0.f);
    float y2 = 0.f;
#pragma unroll
    for (int k = 0; k < 32; k++) y2 = fmaf(__shfl(h, k, 32), sW2[k * 32 + j], y2);
    Yf[t] = y2 * dv;
}
__global__ void scatter2_kernel(const void* ei, const float* __restrict__ Yf,
                                float* __restrict__ A, int E, int n,
                                const int* __restrict__ flags) {
    int idf = flags[1];
    long long t = (long long)blockIdx.x * blockDim.x + threadIdx.x;
    int e = (int)(t >> 5), j = (int)(t & 31);
    if (e >= E) return;
    int s = loadI(ei, e, idf);
    int d = loadI(ei, (long long)E + e, idf);
    if ((unsigned)s >= (unsigned)n || (unsigned)d >= (unsigned)n) return;
    atomicAdd(&A[(size_t)d * 32 + j], Yf[(size_t)s * 32 + j]);
}
__global__ void out_kernel(const float* __restrict__ A, const float* __restrict__ dinv,
                           const void* b2v,
                           const void* Wt1v, const void* bt1v, const void* Wt2v, const void* bt2v,
                           const void* Wa1v, const void* ba1v, const void* Wa2v, const void* ba2v,
                           float* __restrict__ out, int n, const int* __restrict__ flags) {
    __shared__ float sWt1[32 * 16], sWa1[32 * 16], sWt2[16], sWa2[16 * 6];
    __shared__ float sbt1[16], sba1[16], sba2[6], sb2[32];
    __shared__ float sbt2;
    int xf = flags[0];
    int tid = threadIdx.x;
    for (int i = tid; i < 32 * 16; i += blockDim.x) { sWt1[i] = loadF(Wt1v, i, xf); sWa1[i] = loadF(Wa1v, i, xf); }
    for (int i = tid; i < 16 * 6; i += blockDim.x) sWa2[i] = loadF(Wa2v, i, xf);
    if (tid < 16) { sWt2[tid] = loadF(Wt2v, tid, xf); sbt1[tid] = loadF(bt1v, tid, xf); sba1[tid] = loadF(ba1v, tid, xf); }
    if (tid < 32) sb2[tid] = loadF(b2v, tid, xf);
    if (tid < 6) sba2[tid] = loadF(ba2v, tid, xf);
    if (tid == 0) sbt2 = loadF(bt2v, 0, xf);
    __syncthreads();
    long long t = (long long)blockIdx.x * blockDim.x + tid;
    int node = (int)(t >> 5), j = (int)(t & 31);
    if (node >= n) return;
    float* Yf = out + (size_t)n * 7;
    float dv = dinv[node];
    float f = dv * (A[t] + Yf[t]) + sb2[j];
    Yf[t] = f;
    float acc = 0.f;
#pragma unroll
    for (int k = 0; k < 32; k++) {
        float fk = __shfl(f, k, 32);
        float w = (j < 16) ? sWt1[k * 16 + j] : sWa1[k * 16 + (j - 16)];
        acc = fmaf(fk, w, acc);
    }
    float u = fmaxf(acc + ((j < 16) ? sbt1[j] : sba1[j - 16]), 0.f);
    float o = 0.f;
#pragma unroll
    for (int k = 0; k < 16; k++) {
        float ut = __shfl(u, k, 32);
        float ua = __shfl(u, 16 + k, 32);
        float w = (j == 0) ? sWt2[k] : ((j < 7) ? sWa2[k * 6 + (j - 1)] : 0.f);
        o = fmaf((j == 0) ? ut : ua, w, o);
    }
    if (j == 0)      out[node] = o + sbt2;
    else if (j < 4)  out[(size_t)n     + (size_t)node * 3 + (j - 1)] = o + sba2[j - 1];
    else if (j < 7)  out[(size_t)n * 4 + (size_t)node * 3 + (j - 4)] = o + sba2[j - 1];
}

extern "C" void kernel_launch(void* const* d_in, const int* in_sizes, int n_in,
                              void* d_out, int out_size, void* d_ws, size_t ws_size,
                              hipStream_t stream) {
    const void* x   = d_in[0];
    const void* ei  = d_in[1];
    const void* W1  = d_in[2];
    const void* b1  = d_in[3];
    const void* W2  = d_in[4];
    const void* b2  = d_in[5];
    const void* Wt1 = d_in[6];
    const void* bt1 = d_in[7];
    const void* Wt2 = d_in[8];
    const void* bt2 = d_in[9];
    const void* Wa1 = d_in[10];
    const void* ba1 = d_in[11];
    const void* Wa2 = d_in[12];
    const void* ba2 = d_in[13];

    int n = in_sizes[0] / 6;          // 150000
    int E = in_sizes[1] / 2;          // 2400000

    const int B = 256;
    float* out = (float*)d_out;
    char* ws = (char*)d_ws;

    // ---------------- workspace (4B words); Y2b overlays dead packed ----------------
    int NB = (n + 63) >> 6;
    size_t NBw = (size_t)((NB + 63) & ~63);
    size_t nw  = (size_t)((n + 63) & ~63);
    size_t Ew  = (size_t)((E + 63) & ~63);
    size_t Mw  = (16 * nw > Ew) ? 16 * nw : Ew;   // union(packed, Y2b)
    size_t w_bcnt = 0;
    size_t w_bcur = NBw;
    size_t w_boff = 2 * NBw;               // NB+1 entries
    size_t w_par  = 3 * NBw + 64;
    size_t w_flg  = w_par + 256;
    size_t w_row  = w_flg + 64;            // rowptr: n+1
    size_t w_div  = w_row + nw + 64;
    size_t w_z    = w_div + nw;            // z: n x 8 f32 (32B rows)
    size_t w_un   = w_z + 8 * nw;          // union: packed (build) then Y2b (gcn)
    size_t w_adj  = w_un + Mw;
    size_t need   = (w_adj + Ew) * 4;

    if (ws_size >= need && n < (1 << 26)) {
        int*      bcnt    = (int*)(ws + w_bcnt * 4);
        int*      bcur    = (int*)(ws + w_bcur * 4);
        int*      boff    = (int*)(ws + w_boff * 4);
        int*      partial = (int*)(ws + w_par * 4);
        int*      flags   = (int*)(ws + w_flg * 4);
        int*      rowptr  = (int*)(ws + w_row * 4);
        float*    dinv    = (float*)(ws + w_div * 4);
        float*    z       = (float*)(ws + w_z * 4);
        unsigned* packed  = (unsigned*)(ws + w_un * 4);
        bf16*     Y2b     = (bf16*)(ws + w_un * 4);
        int*      adj     = (int*)(ws + w_adj * 4);

        int npart = (NB + 1023) / 1024;
        int grid_e = (E + B - 1) / B;
        int grid_nodes32 = (int)(((long long)n * 32 + B - 1) / B);

        sniff_kernel<<<1, 64, 0, stream>>>(x, ei, flags);
        zero_i32<<<(int)((2 * NBw + B - 1) / B), B, 0, stream>>>(bcnt, (long long)(2 * NBw)); // bcnt+bcur
        bucket_count_glob<<<grid_e, B, 0, stream>>>(ei, bcnt, E, n, flags);
        partial_kernel<<<npart, B, 0, stream>>>(bcnt, partial, NB);
        scanpart_kernel<<<1, B, 0, stream>>>(partial, boff, npart, NB);
        scanblk_kernel<<<npart, B, 0, stream>>>(bcnt, partial, boff, NB);
        bucket_fill_glob<<<grid_e, B, 0, stream>>>(ei, boff, bcur, packed, E, n, flags);
        bucket_sort<<<NB, B, 0, stream>>>(packed, boff, rowptr, adj, n, NB);
        prep2_kernel<<<(n + B - 1) / B, B, 0, stream>>>(rowptr, x, dinv, z, n, flags);
        gcn1_kernel<<<grid_nodes32, B, 0, stream>>>(rowptr, adj, z, W1, b1, W2, Y2b, n, flags);
        gcn2_kernel<<<grid_nodes32, B, 0, stream>>>(rowptr, adj, Y2b, dinv, b2,
                                                    Wt1, bt1, Wt2, bt2, Wa1, ba1, Wa2, ba2,
                                                    out, n, flags);
        return;
    }

    // ---------------- fallback: round-4 scatter path ----------------
    size_t n_pad = (size_t)((n + 63) & ~63);
    float* A     = (float*)ws;
    float* dinvF = (float*)(ws + (size_t)32 * n * 4);
    int* flagsF  = (int*)(ws + ((size_t)32 * n + n_pad) * 4);
    float* Yf    = out + (size_t)n * 7;

    long long zcnt = (long long)32 * n + (long long)n_pad;
    int grid_zero  = (int)((zcnt + B - 1) / B);
    int grid_zeroA = (int)(((long long)32 * n + B - 1) / B);
    int grid_nodes = (int)(((long long)n * 32 + B - 1) / B);
    int grid_edges = (int)(((long long)E * 32 + B - 1) / B);

    sniff_kernel<<<1, 64, 0, stream>>>(x, ei, flagsF);
    zero_f32<<<grid_zero, B, 0, stream>>>(A, zcnt);
    count_kernel<<<(E + B - 1) / B, B, 0, stream>>>(ei, dinvF, E, n, flagsF);
    dinv_kernel<<<(n + B - 1) / B, B, 0, stream>>>(dinvF, n);
    scatter1_kernel<<<grid_edges, B, 0, stream>>>(ei, x, W1, dinvF, A, E, n, flagsF);
    fused_mid_kernel<<<grid_nodes, B, 0, stream>>>(A, x, dinvF, W1, b1, W2, Yf, n, flagsF);
    zero_f32<<<grid_zeroA, B, 0, stream>>>(A, (long long)32 * n);
    scatter2_kernel<<<grid_edges, B, 0, stream>>>(ei, Yf, A, E, n, flagsF);
    out_kernel<<<grid_nodes, B, 0, stream>>>(A, dinvF, b2, Wt1, bt1, Wt2, bt2,
                                             Wa1, ba1, Wa2, ba2, out, n, flagsF);
}

// Round 9
// 360.423 us; speedup vs baseline: 3.5118x; 2.2665x over previous
//
#include <hip/hip_runtime.h>
#include <hip/hip_bf16.h>

typedef __hip_bfloat16 bf16;

__device__ __forceinline__ float b2f(bf16 v) { return __bfloat162float(v); }
__device__ __forceinline__ bf16  f2b(float v){ return __float2bfloat16(v); }

// dtype-flexible loads (flags resolved at runtime by sniff_kernel; branches are uniform)
__device__ __forceinline__ float loadF(const void* p, int i, int isf32) {
    return isf32 ? ((const float*)p)[i] : b2f(((const bf16*)p)[i]);
}
__device__ __forceinline__ int loadI(const void* p, long long i, int isi64) {
    return isi64 ? (int)((const long long*)p)[i] : ((const int*)p)[i];
}

#define NSBW 512      // super-bucket width (nodes)
#define SBSH 9        // log2(NSBW)
#define CHUNK_A 4096  // edges per pass-A block
#define BCAP 12288    // pass-B LDS edge capacity (48 KB)

// ---------------------------------------------------------------- dtype sniff
__global__ void sniff_kernel(const void* xv, const void* eiv, int* flags) {
    int lane = threadIdx.x;                       // 64 threads
    const bf16* xb = (const bf16*)xv;
    int big = 0;
#pragma unroll
    for (int k = 0; k < 4; k++) {
        float v = fabsf(b2f(xb[lane * 4 + k]));
        if (v > 1e6f) big = 1;
    }
    unsigned long long bigmask = __ballot(big);
    const int* e32 = (const int*)eiv;
    int nz = (lane < 32) ? (e32[2 * lane + 1] != 0) : 0;
    unsigned long long nzmask = __ballot(nz);
    if (lane == 0) {
        flags[0] = (__popcll(bigmask) >= 8) ? 1 : 0;
        flags[1] = (nzmask == 0ULL) ? 1 : 0;
    }
}

// ---------------------------------------------------------------- fills
__global__ void zero_f32(float* __restrict__ p, long long cnt) {
    long long i = (long long)blockIdx.x * blockDim.x + threadIdx.x;
    if (i < cnt) p[i] = 0.f;
}
__global__ void zero_i32(int* __restrict__ p, long long cnt) {
    long long i = (long long)blockIdx.x * blockDim.x + threadIdx.x;
    if (i < cnt) p[i] = 0;
}

// ================================================================ Pass A1: super-bucket counts (padded stride-16)
__global__ void sb_count(const void* ei, int* __restrict__ sbcnt, int E, int n,
                         const int* __restrict__ flags) {
    __shared__ int h[512];
    int tid = threadIdx.x;                        // 256
    h[tid] = 0; h[tid + 256] = 0;
    __syncthreads();
    int idf = flags[1];
    long long bs = (long long)blockIdx.x * CHUNK_A;
#pragma unroll 4
    for (int it = 0; it < CHUNK_A / 256; it++) {
        long long e = bs + it * 256 + tid;
        if (e < E) {
            int s = loadI(ei, e, idf);
            int d = loadI(ei, (long long)E + e, idf);
            if ((unsigned)s < (unsigned)n && (unsigned)d < (unsigned)n)
                atomicAdd(&h[d >> SBSH], 1);
        }
    }
    __syncthreads();
    if (h[tid]) atomicAdd(&sbcnt[tid * 16], h[tid]);
    if (h[tid + 256]) atomicAdd(&sbcnt[(tid + 256) * 16], h[tid + 256]);
}

// ================================================================ scan over NSB (<=512) bins; init sbcur
__global__ void sb_scan(const int* __restrict__ sbcnt, int* __restrict__ sboff,
                        int* __restrict__ sbcur, int NSB) {
    __shared__ int lds[512];
    int t = threadIdx.x;                          // 512
    int v = (t < NSB) ? sbcnt[t * 16] : 0;
    lds[t] = v; __syncthreads();
    for (int off = 1; off < 512; off <<= 1) {
        int tv = (t >= off) ? lds[t - off] : 0;
        __syncthreads();
        lds[t] += tv;
        __syncthreads();
    }
    if (t < NSB) { int ex = lds[t] - v; sboff[t] = ex; sbcur[t * 16] = ex; }
    if (t == 0) sboff[NSB] = lds[511];            // grand total
}

// ================================================================ Pass A2: run-reserved scatter into tmp (packed)
__global__ void sb_scatter(const void* ei, int* __restrict__ sbcur,
                           unsigned* __restrict__ tmp, int E, int n,
                           const int* __restrict__ flags) {
    __shared__ int h[512];
    __shared__ int base[512];
    int tid = threadIdx.x;                        // 256
    h[tid] = 0; h[tid + 256] = 0;
    __syncthreads();
    int idf = flags[1];
    long long bs = (long long)blockIdx.x * CHUNK_A;
    // phase 1: local count
#pragma unroll 4
    for (int it = 0; it < CHUNK_A / 256; it++) {
        long long e = bs + it * 256 + tid;
        if (e < E) {
            int s = loadI(ei, e, idf);
            int d = loadI(ei, (long long)E + e, idf);
            if ((unsigned)s < (unsigned)n && (unsigned)d < (unsigned)n)
                atomicAdd(&h[d >> SBSH], 1);
        }
    }
    __syncthreads();
    // phase 2: reserve contiguous runs (padded global cursors), reset own counters
    int c0 = h[tid];       if (c0) base[tid] = atomicAdd(&sbcur[tid * 16], c0);
    int c1 = h[tid + 256]; if (c1) base[tid + 256] = atomicAdd(&sbcur[(tid + 256) * 16], c1);
    h[tid] = 0; h[tid + 256] = 0;
    __syncthreads();
    // phase 3: rank + write (runs of ~14 edges -> near-full-line writes)
#pragma unroll 4
    for (int it = 0; it < CHUNK_A / 256; it++) {
        long long e = bs + it * 256 + tid;
        if (e < E) {
            int s = loadI(ei, e, idf);
            int d = loadI(ei, (long long)E + e, idf);
            if ((unsigned)s < (unsigned)n && (unsigned)d < (unsigned)n) {
                int b = d >> SBSH;
                int r = atomicAdd(&h[b], 1);
                tmp[base[b] + r] = (unsigned)s | ((unsigned)(d & (NSBW - 1)) << 18);
            }
        }
    }
}

// ================================================================ Pass B: per-super-bucket exact CSR (LDS sort)
__global__ __launch_bounds__(512) void sb_sort(const unsigned* __restrict__ tmp,
                                               const int* __restrict__ sboff,
                                               int* __restrict__ rowptr, int* __restrict__ adj,
                                               int n, int NSB) {
    __shared__ unsigned buf[BCAP];                // 48 KB
    __shared__ int deg[NSBW], sc[NSBW], excl[NSBW], cur[NSBW];
    int sb = blockIdx.x, tid = threadIdx.x;       // 512 threads
    int beg = sboff[sb], end = sboff[sb + 1], len = end - beg;
    deg[tid] = 0; cur[tid] = 0;
    __syncthreads();
    bool fits = (len <= BCAP);
    for (int i = tid; i < len; i += 512) {
        unsigned p = tmp[beg + i];
        if (fits) buf[i] = p;
        atomicAdd(&deg[p >> 18], 1);
    }
    __syncthreads();
    sc[tid] = deg[tid]; __syncthreads();
    for (int off = 1; off < 512; off <<= 1) {     // Hillis-Steele inclusive scan
        int tv = (tid >= off) ? sc[tid - off] : 0;
        __syncthreads();
        sc[tid] += tv;
        __syncthreads();
    }
    excl[tid] = sc[tid] - deg[tid];
    int node = (sb << SBSH) + tid;
    if (node < n) rowptr[node] = beg + excl[tid];
    if (sb == 0 && tid == 0) rowptr[n] = sboff[NSB];
    __syncthreads();
    for (int i = tid; i < len; i += 512) {
        unsigned p = fits ? buf[i] : tmp[beg + i];
        int dl = (int)(p >> 18);
        int pos = excl[dl] + atomicAdd(&cur[dl], 1);
        adj[beg + pos] = (int)(p & 0x3FFFFu);     // block-private window: ~1x write amp
    }
}

// dinv + z = [x*dinv(6), dinv, 0] from rowptr degree
__global__ void prep2_kernel(const int* __restrict__ rowptr, const void* xv,
                             float* __restrict__ dinv, float* __restrict__ z,
                             int n, const int* __restrict__ flags) {
    int i = blockIdx.x * blockDim.x + threadIdx.x;
    if (i >= n) return;
    int xf = flags[0];
    int deg = rowptr[i + 1] - rowptr[i];
    float dv = rsqrtf((float)deg + 1.0f);
    dinv[i] = dv;
    float* zr = z + (size_t)i * 8;
#pragma unroll
    for (int k = 0; k < 6; k++) zr[k] = loadF(xv, i * 6 + k, xf) * dv;
    zr[6] = dv; zr[7] = 0.f;
}

// ================================================================ layer 1: per-node gather (proven)
__global__ void gcn1_kernel(const int* __restrict__ rowptr, const int* __restrict__ adj,
                            const float* __restrict__ z,
                            const void* W1v, const void* b1v, const void* W2v,
                            bf16* __restrict__ Y2b, int n, const int* __restrict__ flags) {
    __shared__ float sW1[6 * 32];
    __shared__ float sW2[32 * 32];
    __shared__ float sb1[32];
    int xf = flags[0];
    int tid = threadIdx.x;
    if (tid < 192) sW1[tid] = loadF(W1v, tid, xf);
    for (int i = tid; i < 1024; i += blockDim.x) sW2[i] = loadF(W2v, i, xf);
    if (tid < 32) sb1[tid] = loadF(b1v, tid, xf);
    __syncthreads();
    long long t = (long long)blockIdx.x * blockDim.x + tid;
    int node = (int)(t >> 5), j = (int)(t & 31);
    if (node >= n) return;
    int base = rowptr[node], end = rowptr[node + 1];
    float a0 = 0.f, a1 = 0.f, a2 = 0.f, a3 = 0.f;
    int half4 = (j & 1) * 4;
    for (int i0 = base; i0 < end; i0 += 16) {
        int eidx = i0 + (j >> 1);
        if (eidx < end) {
            int s = adj[eidx];
            const float4 v = *(const float4*)(z + (size_t)s * 8 + half4);
            a0 += v.x; a1 += v.y; a2 += v.z; a3 += v.w;
        }
    }
#pragma unroll
    for (int off = 2; off <= 16; off <<= 1) {
        a0 += __shfl_xor(a0, off, 32); a1 += __shfl_xor(a1, off, 32);
        a2 += __shfl_xor(a2, off, 32); a3 += __shfl_xor(a3, off, 32);
    }
    float S0 = __shfl(a0, 0, 32), S1 = __shfl(a1, 0, 32), S2 = __shfl(a2, 0, 32);
    float S3 = __shfl(a3, 0, 32), S4 = __shfl(a0, 1, 32), S5 = __shfl(a1, 1, 32);
    const float* zs = z + (size_t)node * 8;
    float dv = zs[6];
    S0 += zs[0]; S1 += zs[1]; S2 += zs[2]; S3 += zs[3]; S4 += zs[4]; S5 += zs[5];
    float v = S0 * sW1[j];
    v = fmaf(S1, sW1[32 + j], v);
    v = fmaf(S2, sW1[64 + j], v);
    v = fmaf(S3, sW1[96 + j], v);
    v = fmaf(S4, sW1[128 + j], v);
    v = fmaf(S5, sW1[160 + j], v);
    float h = fmaxf(fmaf(dv, v, sb1[j]), 0.f);
    float y2 = 0.f;
#pragma unroll
    for (int kk = 0; kk < 32; kk++) y2 = fmaf(__shfl(h, kk, 32), sW2[kk * 32 + j], y2);
    Y2b[(size_t)node * 32 + j] = f2b(y2 * dv);
}

// ================================================================ layer 2: per-node bf16 gather + heads (proven)
// out layout (f32): [logits n][normals 3n][uvs 3n][features 32n]
__global__ void gcn2_kernel(const int* __restrict__ rowptr, const int* __restrict__ adj,
                            const bf16* __restrict__ Y2b, const float* __restrict__ dinv,
                            const void* b2v,
                            const void* Wt1v, const void* bt1v, const void* Wt2v, const void* bt2v,
                            const void* Wa1v, const void* ba1v, const void* Wa2v, const void* ba2v,
                            float* __restrict__ out, int n, const int* __restrict__ flags) {
    __shared__ float sWt1[32 * 16], sWa1[32 * 16], sWt2[16], sWa2[16 * 6];
    __shared__ float sbt1[16], sba1[16], sba2[6], sb2[32];
    __shared__ float sbt2;
    int xf = flags[0];
    int tid = threadIdx.x;
    for (int i = tid; i < 32 * 16; i += blockDim.x) {
        sWt1[i] = loadF(Wt1v, i, xf);
        sWa1[i] = loadF(Wa1v, i, xf);
    }
    for (int i = tid; i < 16 * 6; i += blockDim.x) sWa2[i] = loadF(Wa2v, i, xf);
    if (tid < 16) { sWt2[tid] = loadF(Wt2v, tid, xf); sbt1[tid] = loadF(bt1v, tid, xf); sba1[tid] = loadF(ba1v, tid, xf); }
    if (tid < 32) sb2[tid] = loadF(b2v, tid, xf);
    if (tid < 6) sba2[tid] = loadF(ba2v, tid, xf);
    if (tid == 0) sbt2 = loadF(bt2v, 0, xf);
    __syncthreads();
    long long t = (long long)blockIdx.x * blockDim.x + tid;
    int node = (int)(t >> 5), j = (int)(t & 31);
    if (node >= n) return;
    int base = rowptr[node], end = rowptr[node + 1];
    float agg = 0.f;
    for (int i0 = base; i0 < end; i0 += 32) {
        int rem = end - i0;
        int sv = (j < rem) ? adj[i0 + j] : 0;
        int mm = (rem < 32) ? rem : 32;
        int kk = 0;
        for (; kk + 4 <= mm; kk += 4) {
            int s0 = __shfl(sv, kk, 32), s1 = __shfl(sv, kk + 1, 32);
            int s2 = __shfl(sv, kk + 2, 32), s3 = __shfl(sv, kk + 3, 32);
            float q0 = b2f(Y2b[(size_t)s0 * 32 + j]);
            float q1 = b2f(Y2b[(size_t)s1 * 32 + j]);
            float q2 = b2f(Y2b[(size_t)s2 * 32 + j]);
            float q3 = b2f(Y2b[(size_t)s3 * 32 + j]);
            agg += (q0 + q1) + (q2 + q3);
        }
        for (; kk < mm; kk++) {
            int s0 = __shfl(sv, kk, 32);
            agg += b2f(Y2b[(size_t)s0 * 32 + j]);
        }
    }
    float dv = dinv[node];
    float f = fmaf(dv, agg + b2f(Y2b[(size_t)node * 32 + j]), sb2[j]);
    __builtin_nontemporal_store(f, &out[(size_t)n * 7 + (size_t)node * 32 + j]);  // features
    float acc = 0.f;
#pragma unroll
    for (int k = 0; k < 32; k++) {
        float fk = __shfl(f, k, 32);
        float w = (j < 16) ? sWt1[k * 16 + j] : sWa1[k * 16 + (j - 16)];
        acc = fmaf(fk, w, acc);
    }
    float u = fmaxf(acc + ((j < 16) ? sbt1[j] : sba1[j - 16]), 0.f);
    float o = 0.f;
#pragma unroll
    for (int k = 0; k < 16; k++) {
        float ut = __shfl(u, k, 32);
        float ua = __shfl(u, 16 + k, 32);
        float w = (j == 0) ? sWt2[k] : ((j < 7) ? sWa2[k * 6 + (j - 1)] : 0.f);
        o = fmaf((j == 0) ? ut : ua, w, o);
    }
    if (j == 0)      out[node] = o + sbt2;
    else if (j < 4)  out[(size_t)n     + (size_t)node * 3 + (j - 1)] = o + sba2[j - 1];
    else if (j < 7)  out[(size_t)n * 4 + (size_t)node * 3 + (j - 4)] = o + sba2[j - 1];
}

// ================================================================ fallback (round-4 scatter path)
__global__ void count_kernel(const void* ei, float* __restrict__ deg, int E, int n,
                             const int* __restrict__ flags) {
    int e = blockIdx.x * blockDim.x + threadIdx.x;
    if (e >= E) return;
    int d = loadI(ei, (long long)E + e, flags[1]);
    if ((unsigned)d < (unsigned)n) atomicAdd(&deg[d], 1.0f);
}
__global__ void dinv_kernel(float* __restrict__ dinv, int n) {
    int i = blockIdx.x * blockDim.x + threadIdx.x;
    if (i < n) dinv[i] = rsqrtf(dinv[i] + 1.0f);
}
__global__ void scatter1_kernel(const void* ei, const void* xv, const void* W1v,
                                const float* __restrict__ dinv, float* __restrict__ A,
                                int E, int n, const int* __restrict__ flags) {
    __shared__ float sW1[6 * 32];
    int xf = flags[0], idf = flags[1];
    int tid = threadIdx.x;
    if (tid < 192) sW1[tid] = loadF(W1v, tid, xf);
    __syncthreads();
    long long t = (long long)blockIdx.x * blockDim.x + tid;
    int e = (int)(t >> 5), j = (int)(t & 31);
    if (e >= E) return;
    int s = loadI(ei, e, idf);
    int d = loadI(ei, (long long)E + e, idf);
    if ((unsigned)s >= (unsigned)n || (unsigned)d >= (unsigned)n) return;
    float dv = dinv[s];
    float y = 0.f;
#pragma unroll
    for (int k = 0; k < 6; k++) y = fmaf(loadF(xv, s * 6 + k, xf), sW1[k * 32 + j], y);
    atomicAdd(&A[(size_t)d * 32 + j], y * dv);
}
__global__ void fused_mid_kernel(const float* __restrict__ A, const void* xv,
                                 const float* __restrict__ dinv,
                                 const void* W1v, const void* b1v, const void* W2v,
                                 float* __restrict__ Yf, int n, const int* __restrict__ flags) {
    __shared__ float sW1[6 * 32];
    __shared__ float sW2[32 * 32];
    __shared__ float sb1[32];
    int xf = flags[0];
    int tid = threadIdx.x;
    if (tid < 192) sW1[tid] = loadF(W1v, tid, xf);
    for (int i = tid; i < 32 * 32; i += blockDim.x) sW2[i] = loadF(W2v, i, xf);
    if (tid < 32) sb1[tid] = loadF(b1v, tid, xf);
    __syncthreads();
    long long t = (long long)blockIdx.x * blockDim.x + tid;
    int node = (int)(t >> 5), j = (int)(t & 31);
    if (node >= n) return;
    float dv = dinv[node];
    float xw = 0.f;
#pragma unroll
    for (int k = 0; k < 6; k++) xw = fmaf(loadF(xv, node * 6 + k, xf), sW1[k * 32 + j], xw);
    float h = fmaxf(dv * A[t] + dv * dv * xw + sb1[j], 0.f);
    float y2 = 0.f;
#pragma unroll
    for (int k = 0; k < 32; k++) y2 = fmaf(__shfl(h, k, 32), sW2[k * 32 + j], y2);
    Yf[t] = y2 * dv;
}
__global__ void scatter2_kernel(const void* ei, const float* __restrict__ Yf,
                                float* __restrict__ A, int E, int n,
                                const int* __restrict__ flags) {
    int idf = flags[1];
    long long t = (long long)blockIdx.x * blockDim.x + threadIdx.x;
    int e = (int)(t >> 5), j = (int)(t & 31);
    if (e >= E) return;
    int s = loadI(ei, e, idf);
    int d = loadI(ei, (long long)E + e, idf);
    if ((unsigned)s >= (unsigned)n || (unsigned)d >= (unsigned)n) return;
    atomicAdd(&A[(size_t)d * 32 + j], Yf[(size_t)s * 32 + j]);
}
__global__ void out_kernel(const float* __restrict__ A, const float* __restrict__ dinv,
                           const void* b2v,
                           const void* Wt1v, const void* bt1v, const void* Wt2v, const void* bt2v,
                           const void* Wa1v, const void* ba1v, const void* Wa2v, const void* ba2v,
                           float* __restrict__ out, int n, const int* __restrict__ flags) {
    __shared__ float sWt1[32 * 16], sWa1[32 * 16], sWt2[16], sWa2[16 * 6];
    __shared__ float sbt1[16], sba1[16], sba2[6], sb2[32];
    __shared__ float sbt2;
    int xf = flags[0];
    int tid = threadIdx.x;
    for (int i = tid; i < 32 * 16; i += blockDim.x) { sWt1[i] = loadF(Wt1v, i, xf); sWa1[i] = loadF(Wa1v, i, xf); }
    for (int i = tid; i < 16 * 6; i += blockDim.x) sWa2[i] = loadF(Wa2v, i, xf);
    if (tid < 16) { sWt2[tid] = loadF(Wt2v, tid, xf); sbt1[tid] = loadF(bt1v, tid, xf); sba1[tid] = loadF(ba1v, tid, xf); }
    if (tid < 32) sb2[tid] = loadF(b2v, tid, xf);
    if (tid < 6) sba2[tid] = loadF(ba2v, tid, xf);
    if (tid == 0) sbt2 = loadF(bt2v, 0, xf);
    __syncthreads();
    long long t = (long long)blockIdx.x * blockDim.x + tid;
    int node = (int)(t >> 5), j = (int)(t & 31);
    if (node >= n) return;
    float* Yf = out + (size_t)n * 7;
    float dv = dinv[node];
    float f = dv * (A[t] + Yf[t]) + sb2[j];
    Yf[t] = f;
    float acc = 0.f;
#pragma unroll
    for (int k = 0; k < 32; k++) {
        float fk = __shfl(f, k, 32);
        float w = (j < 16) ? sWt1[k * 16 + j] : sWa1[k * 16 + (j - 16)];
        acc = fmaf(fk, w, acc);
    }
    float u = fmaxf(acc + ((j < 16) ? sbt1[j] : sba1[j - 16]), 0.f);
    float o = 0.f;
#pragma unroll
    for (int k = 0; k < 16; k++) {
        float ut = __shfl(u, k, 32);
        float ua = __shfl(u, 16 + k, 32);
        float w = (j == 0) ? sWt2[k] : ((j < 7) ? sWa2[k * 6 + (j - 1)] : 0.f);
        o = fmaf((j == 0) ? ut : ua, w, o);
    }
    if (j == 0)      out[node] = o + sbt2;
    else if (j < 4)  out[(size_t)n     + (size_t)node * 3 + (j - 1)] = o + sba2[j - 1];
    else if (j < 7)  out[(size_t)n * 4 + (size_t)node * 3 + (j - 4)] = o + sba2[j - 1];
}

extern "C" void kernel_launch(void* const* d_in, const int* in_sizes, int n_in,
                              void* d_out, int out_size, void* d_ws, size_t ws_size,
                              hipStream_t stream) {
    const void* x   = d_in[0];
    const void* ei  = d_in[1];
    const void* W1  = d_in[2];
    const void* b1  = d_in[3];
    const void* W2  = d_in[4];
    const void* b2  = d_in[5];
    const void* Wt1 = d_in[6];
    const void* bt1 = d_in[7];
    const void* Wt2 = d_in[8];
    const void* bt2 = d_in[9];
    const void* Wa1 = d_in[10];
    const void* ba1 = d_in[11];
    const void* Wa2 = d_in[12];
    const void* ba2 = d_in[13];

    int n = in_sizes[0] / 6;          // 150000
    int E = in_sizes[1] / 2;          // 2400000

    const int B = 256;
    float* out = (float*)d_out;
    char* ws = (char*)d_ws;

    // ---------------- workspace (4B words) ----------------
    int NSB = (n + NSBW - 1) >> SBSH;              // super-buckets (<=512 when n<=2^18)
    size_t nw  = (size_t)((n + 63) & ~63);
    size_t Ew  = (size_t)((E + 63) & ~63);
    size_t Mw  = (16 * nw > Ew) ? 16 * nw : Ew;    // union(tmp, Y2b)
    size_t w_sbc = 0;                              // sbcnt padded x16: 8192
    size_t w_sbo = 8192;                           // sboff: 513 -> 576
    size_t w_scu = 8192 + 576;                     // sbcur padded x16: 8192
    size_t w_flg = w_scu + 8192;
    size_t w_row = w_flg + 64;                     // rowptr n+1
    size_t w_div = w_row + nw + 64;
    size_t w_z   = w_div + nw;                     // z: n x 8 f32
    size_t w_un  = w_z + 8 * nw;                   // union: tmp (build) then Y2b (gcn)
    size_t w_adj = w_un + Mw;
    size_t need  = (w_adj + Ew) * 4;

    if (ws_size >= need && n <= (1 << 18)) {
        int*      sbcnt = (int*)(ws + w_sbc * 4);
        int*      sboff = (int*)(ws + w_sbo * 4);
        int*      sbcur = (int*)(ws + w_scu * 4);
        int*      flags = (int*)(ws + w_flg * 4);
        int*      rowptr= (int*)(ws + w_row * 4);
        float*    dinv  = (float*)(ws + w_div * 4);
        float*    z     = (float*)(ws + w_z * 4);
        unsigned* tmp   = (unsigned*)(ws + w_un * 4);
        bf16*     Y2b   = (bf16*)(ws + w_un * 4);
        int*      adj   = (int*)(ws + w_adj * 4);

        int grid_a = (int)(((long long)E + CHUNK_A - 1) / CHUNK_A);
        int grid_nodes32 = (int)(((long long)n * 32 + B - 1) / B);

        sniff_kernel<<<1, 64, 0, stream>>>(x, ei, flags);
        zero_i32<<<(8192 * 2 + 576 + B - 1) / B, B, 0, stream>>>(sbcnt, 8192 * 2 + 576); // sbcnt+sboff+sbcur region
        sb_count<<<grid_a, B, 0, stream>>>(ei, sbcnt, E, n, flags);
        sb_scan<<<1, 512, 0, stream>>>(sbcnt, sboff, sbcur, NSB);
        sb_scatter<<<grid_a, B, 0, stream>>>(ei, sbcur, tmp, E, n, flags);
        sb_sort<<<NSB, 512, 0, stream>>>(tmp, sboff, rowptr, adj, n, NSB);
        prep2_kernel<<<(n + B - 1) / B, B, 0, stream>>>(rowptr, x, dinv, z, n, flags);
        gcn1_kernel<<<grid_nodes32, B, 0, stream>>>(rowptr, adj, z, W1, b1, W2, Y2b, n, flags);
        gcn2_kernel<<<grid_nodes32, B, 0, stream>>>(rowptr, adj, Y2b, dinv, b2,
                                                    Wt1, bt1, Wt2, bt2, Wa1, ba1, Wa2, ba2,
                                                    out, n, flags);
        return;
    }

    // ---------------- fallback: round-4 scatter path ----------------
    size_t n_pad = (size_t)((n + 63) & ~63);
    float* A     = (float*)ws;
    float* dinvF = (float*)(ws + (size_t)32 * n * 4);
    int* flagsF  = (int*)(ws + ((size_t)32 * n + n_pad) * 4);
    float* Yf    = out + (size_t)n * 7;

    long long zcnt = (long long)32 * n + (long long)n_pad;
    int grid_zero  = (int)((zcnt + B - 1) / B);
    int grid_zeroA = (int)(((long long)32 * n + B - 1) / B);
    int grid_nodes = (int)(((long long)n * 32 + B - 1) / B);
    int grid_edges = (int)(((long long)E * 32 + B - 1) / B);

    sniff_kernel<<<1, 64, 0, stream>>>(x, ei, flagsF);
    zero_f32<<<grid_zero, B, 0, stream>>>(A, zcnt);
    count_kernel<<<(E + B - 1) / B, B, 0, stream>>>(ei, dinvF, E, n, flagsF);
    dinv_kernel<<<(n + B - 1) / B, B, 0, stream>>>(dinvF, n);
    scatter1_kernel<<<grid_edges, B, 0, stream>>>(ei, x, W1, dinvF, A, E, n, flagsF);
    fused_mid_kernel<<<grid_nodes, B, 0, stream>>>(A, x, dinvF, W1, b1, W2, Yf, n, flagsF);
    zero_f32<<<grid_zeroA, B, 0, stream>>>(A, (long long)32 * n);
    scatter2_kernel<<<grid_edges, B, 0, stream>>>(ei, Yf, A, E, n, flagsF);
    out_kernel<<<grid_nodes, B, 0, stream>>>(A, dinvF, b2, Wt1, bt1, Wt2, bt2,
                                             Wa1, ba1, Wa2, ba2, out, n, flagsF);
}